// Round 16
// baseline (72.233 us; speedup 1.0000x reference)
//
#include <hip/hip_runtime.h>
#include <stdint.h>

// Problem constants: IMG=512, CUT_SIZE=224, CUTN=64, B=4, C=3; sizes in [224,511]
constexpr int S   = 224;
constexpr int Wim = 512;
constexpr int PLANES = 12;                           // B*C
constexpr int N   = 64;
constexpr int HPAIRS = S / 2;                        // 112 row-pairs per plane
constexpr int TOTAL_PAIRS = N * PLANES * HPAIRS;     // 86016
constexpr int WPB   = 4;                             // waves/block, 1 row-pair each
constexpr int GRID  = TOTAL_PAIRS / WPB;             // 21504
constexpr int BUFD  = 544;                           // dwords per row buffer (512 + pad)

typedef float f32x4 __attribute__((ext_vector_type(4)));

__device__ __forceinline__ void vparams(int i, float scale, int sz,
                                        int& ay, float& fy) {
    // frac BEFORE clamp (reference); clamp engages only where frac==0 -> exact
    const float sy  = fmaxf(scale * ((float)i + 0.5f) - 0.5f, 0.0f);
    const float fiy = floorf(sy);
    const int   iy0 = (int)fiy;
    ay = min(iy0, sz - 2);                  // rows [ay, ay+1] always in-image
    fy = (sy - fiy) + (float)(iy0 - ay);    // exactly 1.0 in the clamped case
}

__global__ __launch_bounds__(256) void cutouts_kernel(
    const float* __restrict__ x,
    const int*   __restrict__ sizes,
    const int*   __restrict__ offx,
    const int*   __restrict__ offy,
    float*       __restrict__ out)
{
    __shared__ float lds[WPB][2][BUFD];              // ~17 KiB/block

    const int lane = threadIdx.x & 63;
    const int wv   = threadIdx.x >> 6;

    // FLAT decode (R16: the ONLY change vs R9) — consecutive blocks write
    // consecutive 8-row chunks of the output: compact sequential write front.
    const int pair = blockIdx.x * WPB + wv;          // [0, 86016)
    const int n    = pair / (PLANES * HPAIRS);       // cutout
    const int r2   = pair - n * (PLANES * HPAIRS);
    const int pi   = r2 / HPAIRS;                    // plane = b*C+c
    const int mp   = r2 - pi * HPAIRS;
    const int i0   = 2 * mp;                         // first output row of the pair

    const int   sz    = sizes[n];
    const float scale = (float)sz / (float)S;
    const int   oy    = offy[n];
    const int   ox    = offx[n];
    const float* plane = x + (size_t)pi * (Wim * Wim);

    // column window: float4 index base4..base4+127 covers all needed cols
    const int base4  = ox >> 2;
    const int shift  = ox & 3;
    const int lastc4 = 127 - base4;                  // last in-image col4 offset
    const int K4     = (shift + sz + 5) >> 2;        // float4s needed (incl. wt-0 tail)
    const bool hi    = K4 > 64;                      // wave-uniform

    int ay0, ay1; float fy0, fy1;
    vparams(i0,     scale, sz, ay0, fy0);
    vparams(i0 + 1, scale, sz, ay1, fy1);

    const int cA = min(lane, lastc4);                // clamped (dup loads, same line)
    const int cB = min(lane + 64, lastc4);

    const float* rA = plane + (size_t)(oy + ay0) * Wim + 4 * base4;
    const float* rB = plane + (size_t)(oy + ay1) * Wim + 4 * base4;

    // issue ALL global loads up front (both rows of the pair)
    f32x4 p00 = *(const f32x4*)(rA + 4 * cA);
    f32x4 p01 = *(const f32x4*)(rA + Wim + 4 * cA);
    f32x4 p10 = *(const f32x4*)(rB + 4 * cA);
    f32x4 p11 = *(const f32x4*)(rB + Wim + 4 * cA);
    f32x4 q00{}, q01{}, q10{}, q11{};
    if (hi) {
        q00 = *(const f32x4*)(rA + 4 * cB);
        q01 = *(const f32x4*)(rA + Wim + 4 * cB);
        q10 = *(const f32x4*)(rB + 4 * cB);
        q11 = *(const f32x4*)(rB + Wim + 4 * cB);
    }

    float* buf0 = &lds[wv][0][0];
    float* buf1 = &lds[wv][1][0];

    // vertical blend in regs -> LDS (both rows before any read: one lgkm drain)
    {
        f32x4 w0 = p00 + (p01 - p00) * fy0;
        f32x4 w1 = p10 + (p11 - p10) * fy1;
        if (lane > lastc4) { w0 = f32x4{0.f,0.f,0.f,0.f}; w1 = f32x4{0.f,0.f,0.f,0.f}; }
        *(f32x4*)(buf0 + 4 * lane) = w0;
        *(f32x4*)(buf1 + 4 * lane) = w1;
        if (hi) {
            f32x4 h0 = q00 + (q01 - q00) * fy0;
            f32x4 h1 = q10 + (q11 - q10) * fy1;
            if (lane + 64 > lastc4) { h0 = f32x4{0.f,0.f,0.f,0.f}; h1 = f32x4{0.f,0.f,0.f,0.f}; }
            *(f32x4*)(buf0 + 4 * (lane + 64)) = h0;
            *(f32x4*)(buf1 + 4 * (lane + 64)) = h1;
        }
    }

    // horizontal pass: stride-1 lane mapping; d/fx computed once, both rows
    float* orow0 = out + (size_t)(n * PLANES + pi) * (S * S) + (size_t)i0 * S;
    float* orow1 = orow0 + S;
    #pragma unroll
    for (int r = 0; r < 4; ++r) {
        const int px = r * 64 + lane;
        if (r < 3 || lane < 32) {                    // 224 = 3*64 + 32
            const float sx  = fmaxf(scale * ((float)px + 0.5f) - 0.5f, 0.0f);
            const float fix = floorf(sx);
            const float fx  = sx - fix;              // ix0 <= sz-1 (proven, sz>=224)
            const int   d   = shift + (int)fix;
            const float a0 = buf0[d], a1 = buf0[d + 1];   // wt-0 OOB slots zeroed
            const float c0 = buf1[d], c1 = buf1[d + 1];
            orow0[px] = a0 + (a1 - a0) * fx;
            orow1[px] = c0 + (c1 - c0) * fx;
        }
    }
}

extern "C" void kernel_launch(void* const* d_in, const int* in_sizes, int n_in,
                              void* d_out, int out_size, void* d_ws, size_t ws_size,
                              hipStream_t stream) {
    const float* x     = (const float*)d_in[0];
    const int*   sizes = (const int*)d_in[1];
    const int*   offx  = (const int*)d_in[2];
    const int*   offy  = (const int*)d_in[3];
    float* out = (float*)d_out;

    cutouts_kernel<<<GRID, 256, 0, stream>>>(x, sizes, offx, offy, out);
}

// Round 17
// 50.693 us; speedup vs baseline: 1.4249x; 1.4249x over previous
//
#include <hip/hip_runtime.h>
#include <stdint.h>

// Problem constants: IMG=512, CUT_SIZE=224, CUTN=64, B=4, C=3; sizes in [224,511]
constexpr int S   = 224;
constexpr int Wim = 512;
constexpr int Him = 512;
constexpr int PLANES = 12;                   // B*C
constexpr int N   = 64;
constexpr int SB  = 16;                      // source rows per band
constexpr int NBANDS = Him / SB;             // 32
constexpr int NGRP = 8;                      // cutouts per block (= per XCD)
constexpr int TILES = PLANES * NBANDS;       // 384 (plane,band) tiles
constexpr int WPB   = 4;                     // 256 threads
constexpr int GRID  = TILES * 8;             // 3072
constexpr int ROWF  = 516;                   // LDS row stride (512 + zeroed pad)

__device__ __forceinline__ void load_lds16(const float* g, float* l) {
    __builtin_amdgcn_global_load_lds(
        (const __attribute__((address_space(1))) void*)g,
        (__attribute__((address_space(3))) void*)l, 16, 0, 0);
}

// iy0 exactly as reference computes it
__device__ __forceinline__ int iy0_of(int i, float scale, int sz) {
    const float sy = fmaxf(scale * ((float)i + 0.5f) - 0.5f, 0.0f);
    return min((int)floorf(sy), sz - 1);
}

__global__ __launch_bounds__(256) void cutouts_kernel(
    const float* __restrict__ x,
    const int*   __restrict__ sizes,
    const int*   __restrict__ offx,
    const int*   __restrict__ offy,
    float*       __restrict__ out)
{
    __shared__ float lds[SB + 1][ROWF];      // 35,088 B -> 4 blocks/CU

    const int lane = threadIdx.x & 63;
    const int wv   = threadIdx.x >> 6;       // 0..3

    // R17 decode: XCD k owns cutout group g = k (n in [8k, 8k+8)) for ALL tiles.
    // -> each XCD's writes confined to its own contiguous 18.8 MB output slice,
    //    advancing monotonically (8 sequential streams), fill-like.
    const int xcd = blockIdx.x & 7;          // XCD (round-robin dispatch heuristic)
    const int t   = blockIdx.x >> 3;         // tile 0..383, swept in order per XCD
    const int g   = xcd;                     // cutout group == XCD
    const int pi  = t >> 5;                  // plane 0..11
    const int b   = t & 31;                  // band 0..31

    // zero pad cols [512..515] (hit only by weight-0 neighbor reads)
    if (threadIdx.x < (SB + 1) * 4)
        lds[threadIdx.x >> 2][Wim + (threadIdx.x & 3)] = 0.0f;

    // stage band once: 17 rows x 512 floats = 34 chunks of 1 KB DMA
    const float* plane = x + (size_t)pi * (Him * Wim);
    for (int c = wv; c < (SB + 1) * 2; c += WPB) {
        const int row  = c >> 1, half = c & 1;
        const int srow = min(SB * b + row, Him - 1);   // dup row (wt-0 only)
        load_lds16(plane + (size_t)srow * Wim + half * 256 + lane * 4,
                   &lds[row][half * 256]);
    }

    // in-lane parallel first_ge: lanes 0..7 -> i_lo, lanes 8..15 -> i_hi
    int flv;
    {
        const int   idx = lane & 7;
        const int   nn_ = g * NGRP + idx;
        const int   szl = sizes[nn_];
        const int   oyl = offy[nn_];
        const float scl = (float)szl / (float)S;
        const int   P   = SB * b - oyl + ((lane & 8) ? SB : 0);
        int res;
        if (P <= 0) res = 0;
        else if (P > szl - 1) res = S;
        else {
            const float cc = ((float)P + 0.5f) / scl - 0.5f;
            int i = (int)ceilf(fminf(fmaxf(cc, 0.0f), (float)S));
            while (i > 0 && iy0_of(i - 1, scl, szl) >= P) --i;
            while (i < S && iy0_of(i, scl, szl) < P) ++i;
            res = i;
        }
        flv = res;
    }

    asm volatile("s_waitcnt vmcnt(0)" ::: "memory");
    __syncthreads();

    #pragma unroll 1
    for (int nn = 0; nn < NGRP; ++nn) {
        const int i_lo = __builtin_amdgcn_readlane(flv, nn);      // SGPR, uniform
        const int i_hi = __builtin_amdgcn_readlane(flv, nn + 8);
        if (i_lo >= i_hi) continue;                               // scalar branch

        const int n  = g * NGRP + nn;
        const int sz = sizes[n];
        const int oy = offy[n];
        const int ox = offx[n];
        const float scale = (float)sz / (float)S;
        const int   L     = SB * b - oy;

        // horizontal params once per (wave,cutout), reused for all its rows
        int dv[4]; float fxv[4];
        #pragma unroll
        for (int r = 0; r < 4; ++r) {
            const int   px = r * 64 + lane;
            const float sx = fmaxf(scale * ((float)px + 0.5f) - 0.5f, 0.0f);
            const float fi = floorf(sx);
            fxv[r] = sx - fi;                          // ix0 <= sz-1 (sz>=224)
            dv[r]  = ox + (int)fi;                     // d+1 <= 512: pad zeroed
        }

        float* oplane = out + (size_t)(n * PLANES + pi) * (S * S);

        for (int i = i_lo + wv; i < i_hi; i += WPB) {
            const float sy  = fmaxf(scale * ((float)i + 0.5f) - 0.5f, 0.0f);
            const float fiy = floorf(sy);
            const float fy  = sy - fiy;                // frac BEFORE clamp
            const int   rel = (int)fiy - L;            // in [0, SB-1] (partition)
            const float* l0 = &lds[rel][0];
            const float* l1 = &lds[rel + 1][0];        // rel+1 <= SB staged
            float* orow = oplane + (size_t)i * S;

            #pragma unroll
            for (int r = 0; r < 4; ++r) {
                if (r < 3 || lane < 32) {              // 224 = 3*64 + 32
                    const int   d = dv[r];
                    const float f = fxv[r];
                    const float a0 = l0[d], a1 = l0[d + 1];   // ds_read2_b32
                    const float c0 = l1[d], c1 = l1[d + 1];
                    const float top = a0 + (a1 - a0) * f;
                    const float bot = c0 + (c1 - c0) * f;
                    orow[r * 64 + lane] = top + (bot - top) * fy;
                }
            }
        }
    }
}

extern "C" void kernel_launch(void* const* d_in, const int* in_sizes, int n_in,
                              void* d_out, int out_size, void* d_ws, size_t ws_size,
                              hipStream_t stream) {
    const float* x     = (const float*)d_in[0];
    const int*   sizes = (const int*)d_in[1];
    const int*   offx  = (const int*)d_in[2];
    const int*   offy  = (const int*)d_in[3];
    float* out = (float*)d_out;

    cutouts_kernel<<<GRID, 256, 0, stream>>>(x, sizes, offx, offy, out);
}

// Round 18
// 39.726 us; speedup vs baseline: 1.8183x; 1.2760x over previous
//
#include <hip/hip_runtime.h>
#include <stdint.h>

// Problem constants: IMG=512, CUT_SIZE=224, CUTN=64, B=4, C=3; sizes in [224,511]
constexpr int S   = 224;
constexpr int Wim = 512;
constexpr int Him = 512;
constexpr int PLANES = 12;                   // B*C
constexpr int N   = 64;
constexpr int SB  = 16;                      // source rows per band
constexpr int NBANDS = Him / SB;             // 32
constexpr int NGRP = 8;                      // cutouts per block
constexpr int GROUPS = N / NGRP;             // 8
constexpr int TILES = PLANES * NBANDS;       // 384 (plane,band) tiles
constexpr int TPX   = TILES / 8;             // 48 tiles per XCD
constexpr int WPB   = 4;                     // 256 threads
constexpr int GRID  = TILES * GROUPS;        // 3072
constexpr int ROWF  = 516;                   // LDS row stride (512 + zeroed pad)

__device__ __forceinline__ void load_lds16(const float* g, float* l) {
    __builtin_amdgcn_global_load_lds(
        (const __attribute__((address_space(1))) void*)g,
        (__attribute__((address_space(3))) void*)l, 16, 0, 0);
}

// iy0 exactly as reference computes it
__device__ __forceinline__ int iy0_of(int i, float scale, int sz) {
    const float sy = fmaxf(scale * ((float)i + 0.5f) - 0.5f, 0.0f);
    return min((int)floorf(sy), sz - 1);
}

__global__ __launch_bounds__(256) void cutouts_kernel(
    const float* __restrict__ x,
    const int*   __restrict__ sizes,
    const int*   __restrict__ offx,
    const int*   __restrict__ offy,
    float*       __restrict__ out)
{
    __shared__ float lds[SB + 1][ROWF];      // 35,088 B -> 4 blocks/CU

    const int lane = threadIdx.x & 63;
    const int wv   = threadIdx.x >> 6;       // 0..3

    // decode: XCD-affine (plane,band) tile (R12 structure, best @39.5)
    const int xcd   = blockIdx.x & 7;
    const int local = blockIdx.x >> 3;       // 0..383
    const int tk    = local >> 3;            // tile-in-xcd 0..47
    const int g     = local & 7;             // cutout group 0..7
    const int t     = xcd * TPX + tk;        // 0..383
    const int pi    = t >> 5;                // plane 0..11
    const int b     = t & 31;                // band 0..31

    // zero pad cols [512..515] (hit only by weight-0 neighbor reads)
    if (threadIdx.x < (SB + 1) * 4)
        lds[threadIdx.x >> 2][Wim + (threadIdx.x & 3)] = 0.0f;

    // stage band once: 17 rows x 512 floats = 34 chunks of 1 KB DMA
    const float* plane = x + (size_t)pi * (Him * Wim);
    for (int c = wv; c < (SB + 1) * 2; c += WPB) {
        const int row  = c >> 1, half = c & 1;
        const int srow = min(SB * b + row, Him - 1);   // dup row (wt-0 only)
        load_lds16(plane + (size_t)srow * Wim + half * 256 + lane * 4,
                   &lds[row][half * 256]);
    }

    // in-lane parallel first_ge: lanes 0..7 -> i_lo, lanes 8..15 -> i_hi
    int flv;
    {
        const int   idx = lane & 7;
        const int   nn_ = g * NGRP + idx;
        const int   szl = sizes[nn_];
        const int   oyl = offy[nn_];
        const float scl = (float)szl / (float)S;
        const int   P   = SB * b - oyl + ((lane & 8) ? SB : 0);
        int res;
        if (P <= 0) res = 0;
        else if (P > szl - 1) res = S;
        else {
            const float cc = ((float)P + 0.5f) / scl - 0.5f;
            int i = (int)ceilf(fminf(fmaxf(cc, 0.0f), (float)S));
            while (i > 0 && iy0_of(i - 1, scl, szl) >= P) --i;
            while (i < S && iy0_of(i, scl, szl) < P) ++i;
            res = i;
        }
        flv = res;
    }

    asm volatile("s_waitcnt vmcnt(0)" ::: "memory");
    __syncthreads();

    #pragma unroll 1
    for (int nn = 0; nn < NGRP; ++nn) {
        const int i_lo = __builtin_amdgcn_readlane(flv, nn);      // SGPR, uniform
        const int i_hi = __builtin_amdgcn_readlane(flv, nn + 8);
        if (i_lo >= i_hi) continue;                               // scalar branch

        const int n  = g * NGRP + nn;
        const int sz = sizes[n];
        const int oy = offy[n];
        const int ox = offx[n];
        const float scale = (float)sz / (float)S;
        const int   L     = SB * b - oy;

        // horizontal params once per (wave,cutout), reused for all its rows
        int dv[4]; float fxv[4];
        #pragma unroll
        for (int r = 0; r < 4; ++r) {
            const int   px = r * 64 + lane;
            const float sx = fmaxf(scale * ((float)px + 0.5f) - 0.5f, 0.0f);
            const float fi = floorf(sx);
            fxv[r] = sx - fi;                          // ix0 <= sz-1 (sz>=224)
            dv[r]  = ox + (int)fi;                     // d+1 <= 512: pad zeroed
        }

        float* oplane = out + (size_t)(n * PLANES + pi) * (S * S);

        // R18: CONTIGUOUS row run per wave (was stride-4 interleave).
        // Each wave's store stream is now strictly sequential over
        // chunk*896 B (~2.7-12.5 KB, multi-DRAM-page dense). Rotation by nn
        // rebalances the systematic tail-wave underload across cutouts.
        const int span  = i_hi - i_lo;
        const int chunk = (span + WPB - 1) >> 2;
        const int wsel  = (wv + nn) & 3;
        const int is    = i_lo + wsel * chunk;
        const int ie    = min(is + chunk, i_hi);

        for (int i = is; i < ie; ++i) {
            const float sy  = fmaxf(scale * ((float)i + 0.5f) - 0.5f, 0.0f);
            const float fiy = floorf(sy);
            const float fy  = sy - fiy;                // frac BEFORE clamp
            const int   rel = (int)fiy - L;            // in [0, SB-1] (partition)
            const float* l0 = &lds[rel][0];
            const float* l1 = &lds[rel + 1][0];        // rel+1 <= SB staged
            float* orow = oplane + (size_t)i * S;

            #pragma unroll
            for (int r = 0; r < 4; ++r) {
                if (r < 3 || lane < 32) {              // 224 = 3*64 + 32
                    const int   d = dv[r];
                    const float f = fxv[r];
                    const float a0 = l0[d], a1 = l0[d + 1];   // ds_read2_b32
                    const float c0 = l1[d], c1 = l1[d + 1];
                    const float top = a0 + (a1 - a0) * f;
                    const float bot = c0 + (c1 - c0) * f;
                    orow[r * 64 + lane] = top + (bot - top) * fy;
                }
            }
        }
    }
}

extern "C" void kernel_launch(void* const* d_in, const int* in_sizes, int n_in,
                              void* d_out, int out_size, void* d_ws, size_t ws_size,
                              hipStream_t stream) {
    const float* x     = (const float*)d_in[0];
    const int*   sizes = (const int*)d_in[1];
    const int*   offx  = (const int*)d_in[2];
    const int*   offy  = (const int*)d_in[3];
    float* out = (float*)d_out;

    cutouts_kernel<<<GRID, 256, 0, stream>>>(x, sizes, offx, offy, out);
}